// Round 1
// baseline (650.463 us; speedup 1.0000x reference)
//
#include <hip/hip_runtime.h>
#include <math.h>

#define NHEADS 32
#define NKVH 8
#define HD 128
#define BATCH 4
#define SEQ 1024
#define STOK (BATCH*SEQ)
#define NUM_SLOTS 8192
#define SCALE 0.08838834764831845f

typedef __attribute__((ext_vector_type(8))) short short8v;
typedef __attribute__((ext_vector_type(4))) short short4v;
typedef __attribute__((ext_vector_type(4))) float floatx4;

// LDS strides in shorts (chosen for bank behavior + alignment; see analysis)
#define KSTR 136   // 128 + 8: rows 16B-aligned (272B), b128 reads 2-way (free)
#define VSTR 68    // 64 + 4: rows 8B-aligned (136B), b64 writes at 4-access floor, b64 reads conflict-free
#define PSTR 72    // 64 + 8: rows 16B-aligned (144B), b128 reads 2-way (free)
#define BM 128
#define BN 64
#define MT 2
#define QTILES (SEQ/BM)   // 8

__device__ __forceinline__ short f2bf(float f) {
  unsigned u = __builtin_bit_cast(unsigned, f);
  u += 0x7fffu + ((u >> 16) & 1u);
  return (short)(u >> 16);
}

__global__ __launch_bounds__(256)
void attn_prefill(const float* __restrict__ qg,
                  const float* __restrict__ kg,
                  const float* __restrict__ vg,
                  float* __restrict__ og)
{
  __shared__ __align__(16) short ksh[64 * KSTR];
  __shared__ __align__(16) short vsh[128 * VSTR];
  __shared__ __align__(16) short psh[4 * MT * 16 * PSTR];

  const int bx = blockIdx.x;
  const int qt = (QTILES - 1) - (bx & (QTILES - 1));  // longest blocks first
  const int bb = (bx >> 3) & (BATCH - 1);
  const int h  = bx >> 5;
  const int kh = h >> 2;            // GQA: 4 query heads per kv head

  const int tid  = threadIdx.x;
  const int w    = tid >> 6;
  const int lane = tid & 63;
  const int l15  = lane & 15;
  const int quad = lane >> 4;

  const int q0 = qt * BM;

  // ---- Q fragments (pre-scaled, bf16), verified A-layout ----
  short8v qf[MT][4];
  #pragma unroll
  for (int mi = 0; mi < MT; ++mi) {
    const int qrow = q0 + w*32 + mi*16 + l15;
    const float* qp = qg + (size_t)(bb*SEQ + qrow) * (NHEADS*HD) + h*HD + quad*8;
    #pragma unroll
    for (int dc = 0; dc < 4; ++dc) {
      float4 a = *(const float4*)(qp + dc*32);
      float4 c = *(const float4*)(qp + dc*32 + 4);
      short8v f;
      f[0]=f2bf(a.x*SCALE); f[1]=f2bf(a.y*SCALE); f[2]=f2bf(a.z*SCALE); f[3]=f2bf(a.w*SCALE);
      f[4]=f2bf(c.x*SCALE); f[5]=f2bf(c.y*SCALE); f[6]=f2bf(c.z*SCALE); f[7]=f2bf(c.w*SCALE);
      qf[mi][dc] = f;
    }
  }

  floatx4 oacc[MT][8];
  float mrun[MT][4], lrun[MT][4];
  #pragma unroll
  for (int mi = 0; mi < MT; ++mi) {
    #pragma unroll
    for (int dt = 0; dt < 8; ++dt) oacc[mi][dt] = (floatx4){0.f,0.f,0.f,0.f};
    #pragma unroll
    for (int r = 0; r < 4; ++r) { mrun[mi][r] = -1e30f; lrun[mi][r] = 0.f; }
  }

  const int nTiles = 2*qt + 2;   // causal trim: keys 0 .. q0+127
  for (int it = 0; it < nTiles; ++it) {
    const int n0 = it * BN;
    __syncthreads();
    // ---- stage K tile [64 keys][128 d] -> bf16 LDS row-major ----
    {
      const int c4 = tid & 31;
      const int r0 = tid >> 5;
      #pragma unroll
      for (int rr = 0; rr < 8; ++rr) {
        const int row = r0 + rr*8;
        float4 x = *(const float4*)(kg + (size_t)(bb*SEQ + n0 + row)*(NKVH*HD) + kh*HD + c4*4);
        short4v s;
        s[0]=f2bf(x.x); s[1]=f2bf(x.y); s[2]=f2bf(x.z); s[3]=f2bf(x.w);
        *(short4v*)(&ksh[row*KSTR + c4*4]) = s;
      }
    }
    // ---- stage V tile transposed: Vt[d][key] ----
    {
      const int d   = tid & 127;
      const int kgp = tid >> 7;
      const float* vp = vg + (size_t)(bb*SEQ + n0 + kgp*32)*(NKVH*HD) + kh*HD + d;
      #pragma unroll
      for (int g = 0; g < 8; ++g) {
        const float* p = vp + (size_t)(g*4)*(NKVH*HD);
        float e0 = p[0];
        float e1 = p[NKVH*HD];
        float e2 = p[2*(NKVH*HD)];
        float e3 = p[3*(NKVH*HD)];
        short4v s; s[0]=f2bf(e0); s[1]=f2bf(e1); s[2]=f2bf(e2); s[3]=f2bf(e3);
        *(short4v*)(&vsh[d*VSTR + kgp*32 + g*4]) = s;
      }
    }
    __syncthreads();

    const bool active = (n0 <= q0 + w*32 + 31);
    if (active) {
      // ---- S = Q K^T (2 m-tiles x 64 keys), K frags shared across mi ----
      floatx4 sacc[MT][4];
      #pragma unroll
      for (int mi = 0; mi < MT; ++mi)
        #pragma unroll
        for (int sub = 0; sub < 4; ++sub) sacc[mi][sub] = (floatx4){0.f,0.f,0.f,0.f};
      #pragma unroll
      for (int sub = 0; sub < 4; ++sub) {
        #pragma unroll
        for (int dc = 0; dc < 4; ++dc) {
          short8v kf = *(const short8v*)(&ksh[(sub*16 + l15)*KSTR + dc*32 + quad*8]);
          #pragma unroll
          for (int mi = 0; mi < MT; ++mi)
            sacc[mi][sub] = __builtin_amdgcn_mfma_f32_16x16x32_bf16(qf[mi][dc], kf, sacc[mi][sub], 0, 0, 0);
        }
      }
      // ---- online softmax + P -> LDS (bf16) ----
      #pragma unroll
      for (int mi = 0; mi < MT; ++mi) {
        const int qbase = q0 + w*32 + mi*16;
        float s[4][4];
        const bool needMask = (n0 + BN - 1) > qbase;
        #pragma unroll
        for (int sub = 0; sub < 4; ++sub) {
          const int key = n0 + sub*16 + l15;
          #pragma unroll
          for (int r = 0; r < 4; ++r) {
            float sv = sacc[mi][sub][r];
            if (needMask && key > (qbase + quad*4 + r)) sv = -1e30f;
            s[sub][r] = sv;
          }
        }
        float mloc[4];
        #pragma unroll
        for (int r = 0; r < 4; ++r)
          mloc[r] = fmaxf(fmaxf(s[0][r], s[1][r]), fmaxf(s[2][r], s[3][r]));
        #pragma unroll
        for (int off = 1; off <= 8; off <<= 1)
          #pragma unroll
          for (int r = 0; r < 4; ++r)
            mloc[r] = fmaxf(mloc[r], __shfl_xor(mloc[r], off));
        float alpha[4], rs[4];
        #pragma unroll
        for (int r = 0; r < 4; ++r) {
          float mnew = fmaxf(mrun[mi][r], mloc[r]);
          alpha[r] = __expf(mrun[mi][r] - mnew);
          mrun[mi][r] = mnew;
          rs[r] = 0.f;
        }
        short* pw = &psh[((w*MT + mi)*16)*PSTR];
        #pragma unroll
        for (int sub = 0; sub < 4; ++sub) {
          #pragma unroll
          for (int r = 0; r < 4; ++r) {
            float p = __expf(s[sub][r] - mrun[mi][r]);
            rs[r] += p;
            pw[(quad*4 + r)*PSTR + sub*16 + l15] = f2bf(p);
          }
        }
        #pragma unroll
        for (int off = 1; off <= 8; off <<= 1)
          #pragma unroll
          for (int r = 0; r < 4; ++r)
            rs[r] += __shfl_xor(rs[r], off);
        #pragma unroll
        for (int r = 0; r < 4; ++r)
          lrun[mi][r] = lrun[mi][r]*alpha[r] + rs[r];
        #pragma unroll
        for (int dt = 0; dt < 8; ++dt)
          #pragma unroll
          for (int r = 0; r < 4; ++r)
            oacc[mi][dt][r] *= alpha[r];
      }
      // ---- P fragments (same-wave LDS RAW; DS ops in-order per wave) ----
      short8v pf[MT][2];
      #pragma unroll
      for (int mi = 0; mi < MT; ++mi)
        #pragma unroll
        for (int kc = 0; kc < 2; ++kc)
          pf[mi][kc] = *(const short8v*)(&psh[((w*MT + mi)*16 + l15)*PSTR + kc*32 + quad*8]);
      // ---- O += P V, V frags shared across mi ----
      #pragma unroll
      for (int dt = 0; dt < 8; ++dt) {
        #pragma unroll
        for (int kc = 0; kc < 2; ++kc) {
          const short* vb = &vsh[(dt*16 + l15)*VSTR + kc*32 + quad*8];
          short4v lo = *(const short4v*)(vb);
          short4v hi = *(const short4v*)(vb + 4);
          short8v vf;
          vf[0]=lo[0]; vf[1]=lo[1]; vf[2]=lo[2]; vf[3]=lo[3];
          vf[4]=hi[0]; vf[5]=hi[1]; vf[6]=hi[2]; vf[7]=hi[3];
          #pragma unroll
          for (int mi = 0; mi < MT; ++mi)
            oacc[mi][dt] = __builtin_amdgcn_mfma_f32_16x16x32_bf16(pf[mi][kc], vf, oacc[mi][dt], 0, 0, 0);
        }
      }
    }
  }

  // ---- epilogue: normalize and store ----
  #pragma unroll
  for (int mi = 0; mi < MT; ++mi) {
    float inv[4];
    #pragma unroll
    for (int r = 0; r < 4; ++r) inv[r] = 1.0f / lrun[mi][r];
    #pragma unroll
    for (int dt = 0; dt < 8; ++dt) {
      #pragma unroll
      for (int r = 0; r < 4; ++r) {
        const int qrow = q0 + w*32 + mi*16 + quad*4 + r;
        og[(size_t)(bb*SEQ + qrow)*(NHEADS*HD) + h*HD + dt*16 + l15] = oacc[mi][dt][r] * inv[r];
      }
    }
  }
}

// ---- KV cache: copy pristine input caches to output, then scatter rows ----
__global__ void cache_copy(const float4* __restrict__ kc_in, const float4* __restrict__ vc_in,
                           float4* __restrict__ kc_out, float4* __restrict__ vc_out, int n4)
{
  int i = blockIdx.x * blockDim.x + threadIdx.x;
  const int stride = gridDim.x * blockDim.x;
  for (; i < n4; i += stride) {
    kc_out[i] = kc_in[i];
    vc_out[i] = vc_in[i];
  }
}

__global__ void cache_scatter(const float4* __restrict__ k, const float4* __restrict__ v,
                              const int* __restrict__ slots,
                              float4* __restrict__ kc_out, float4* __restrict__ vc_out)
{
  const int i = blockIdx.x * blockDim.x + threadIdx.x;   // over STOK*256
  const int ROW4 = NKVH*HD/4;                            // 256 float4 per token row
  const int s = i >> 8, c = i & 255;
  const int slot = slots[s];
  kc_out[(size_t)slot*ROW4 + c] = k[i];
  vc_out[(size_t)slot*ROW4 + c] = v[i];
}

extern "C" void kernel_launch(void* const* d_in, const int* in_sizes, int n_in,
                              void* d_out, int out_size, void* d_ws, size_t ws_size,
                              hipStream_t stream)
{
  const float* q     = (const float*)d_in[0];
  const float* k     = (const float*)d_in[1];
  const float* v     = (const float*)d_in[2];
  const float* kc_in = (const float*)d_in[3];
  const float* vc_in = (const float*)d_in[4];
  const int*   slots = (const int*)d_in[5];

  float* o_out  = (float*)d_out;
  float* kc_out = o_out  + (size_t)STOK * NHEADS * HD;
  float* vc_out = kc_out + (size_t)NUM_SLOTS * NKVH * HD;

  attn_prefill<<<NHEADS*BATCH*QTILES, 256, 0, stream>>>(q, k, v, o_out);
  cache_copy<<<2048, 256, 0, stream>>>((const float4*)kc_in, (const float4*)vc_in,
                                       (float4*)kc_out, (float4*)vc_out,
                                       NUM_SLOTS*NKVH*HD/4);
  cache_scatter<<<(STOK*(NKVH*HD/4))/256, 256, 0, stream>>>((const float4*)k, (const float4*)v, slots,
                                                            (float4*)kc_out, (float4*)vc_out);
}

// Round 2
// 465.294 us; speedup vs baseline: 1.3980x; 1.3980x over previous
//
#include <hip/hip_runtime.h>
#include <math.h>

#define NHEADS 32
#define NKVH 8
#define HD 128
#define BATCH 4
#define SEQ 1024
#define STOK (BATCH*SEQ)
#define NUM_SLOTS 8192
#define SCALE 0.08838834764831845f

typedef __attribute__((ext_vector_type(8))) short short8v;
typedef __attribute__((ext_vector_type(4))) short short4v;
typedef __attribute__((ext_vector_type(4))) float floatx4;

// LDS strides in shorts
#define KSTR 136   // 128 + 8: rows 16B-aligned (272B), b128 reads 2-way (free)
#define VSTR 68    // 64 + 4: rows 8B-aligned (136B); b64 frag reads conflict-light
#define PSTR 72    // 64 + 8: rows 16B-aligned (144B), b128 reads 2-way (free)
#define BM 128
#define BN 64
#define MT 2
#define QTILES (SEQ/BM)   // 8

__device__ __forceinline__ short f2bf(float f) {
  unsigned u = __builtin_bit_cast(unsigned, f);
  u += 0x7fffu + ((u >> 16) & 1u);
  return (short)(u >> 16);
}

__global__ __launch_bounds__(256)
void attn_prefill(const float* __restrict__ qg,
                  const float* __restrict__ kg,
                  const float* __restrict__ vg,
                  float* __restrict__ og)
{
  __shared__ __align__(16) short ksh[64 * KSTR];
  __shared__ __align__(16) short vsh[128 * VSTR];
  __shared__ __align__(16) short psh[4 * MT * 16 * PSTR];

  const int bx = blockIdx.x;
  // LPT order: all qt=7 blocks (16 tiles) dispatch first, then qt=6, ...
  const int qt = (QTILES - 1) - (bx >> 7);
  const int pair = bx & 127;
  const int h  = pair >> 2;
  const int bb = pair & 3;
  const int kh = h >> 2;            // GQA: 4 query heads per kv head

  const int tid  = threadIdx.x;
  const int w    = tid >> 6;
  const int lane = tid & 63;
  const int l15  = lane & 15;
  const int quad = lane >> 4;

  const int q0 = qt * BM;

  // ---- Q fragments (pre-scaled, bf16), verified A-layout ----
  short8v qf[MT][4];
  #pragma unroll
  for (int mi = 0; mi < MT; ++mi) {
    const int qrow = q0 + w*32 + mi*16 + l15;
    const float* qp = qg + (size_t)(bb*SEQ + qrow) * (NHEADS*HD) + h*HD + quad*8;
    #pragma unroll
    for (int dc = 0; dc < 4; ++dc) {
      float4 a = *(const float4*)(qp + dc*32);
      float4 c = *(const float4*)(qp + dc*32 + 4);
      short8v f;
      f[0]=f2bf(a.x*SCALE); f[1]=f2bf(a.y*SCALE); f[2]=f2bf(a.z*SCALE); f[3]=f2bf(a.w*SCALE);
      f[4]=f2bf(c.x*SCALE); f[5]=f2bf(c.y*SCALE); f[6]=f2bf(c.z*SCALE); f[7]=f2bf(c.w*SCALE);
      qf[mi][dc] = f;
    }
  }

  floatx4 oacc[MT][8];
  float mrun[MT][4], lrun[MT][4];
  #pragma unroll
  for (int mi = 0; mi < MT; ++mi) {
    #pragma unroll
    for (int dt = 0; dt < 8; ++dt) oacc[mi][dt] = (floatx4){0.f,0.f,0.f,0.f};
    #pragma unroll
    for (int r = 0; r < 4; ++r) { mrun[mi][r] = -1e30f; lrun[mi][r] = 0.f; }
  }

  // staging thread mapping (shared by K and V): 32 lanes sweep d, 8 rows/pass
  const int c4 = tid & 31;     // d4 = c4*4
  const int r0 = tid >> 5;     // row base: rows r0 + 8*pass

  const int nTiles = 2*qt + 2;   // causal trim: keys 0 .. q0+127

  // ---- K prefetch registers (tile 0) ----
  float4 kreg[8];
  {
    const float* kb = kg + (size_t)(bb*SEQ)*(NKVH*HD) + kh*HD + c4*4;
    #pragma unroll
    for (int rr = 0; rr < 8; ++rr)
      kreg[rr] = *(const float4*)(kb + (size_t)(r0 + rr*8)*(NKVH*HD));
  }

  for (int it = 0; it < nTiles; ++it) {
    const int n0 = it * BN;
    __syncthreads();   // previous tile's compute done; LDS reusable

    // ---- write prefetched K tile to LDS (bf16, row-major) ----
    #pragma unroll
    for (int rr = 0; rr < 8; ++rr) {
      short4v s;
      s[0]=f2bf(kreg[rr].x); s[1]=f2bf(kreg[rr].y); s[2]=f2bf(kreg[rr].z); s[3]=f2bf(kreg[rr].w);
      *(short4v*)(&ksh[(r0 + rr*8)*KSTR + c4*4]) = s;
    }
    // ---- stage V tile: coalesced float4 loads, transpose to Vt[d][key] ----
    {
      const float* vb = vg + (size_t)(bb*SEQ + n0)*(NKVH*HD) + kh*HD + c4*4;
      #pragma unroll
      for (int p = 0; p < 8; ++p) {
        const int key = r0 + p*8;
        float4 x = *(const float4*)(vb + (size_t)key*(NKVH*HD));
        vsh[(c4*4+0)*VSTR + key] = f2bf(x.x);
        vsh[(c4*4+1)*VSTR + key] = f2bf(x.y);
        vsh[(c4*4+2)*VSTR + key] = f2bf(x.z);
        vsh[(c4*4+3)*VSTR + key] = f2bf(x.w);
      }
    }
    __syncthreads();

    // ---- prefetch next K tile (overlaps with compute below) ----
    if (it + 1 < nTiles) {
      const float* kb = kg + (size_t)(bb*SEQ + n0 + BN)*(NKVH*HD) + kh*HD + c4*4;
      #pragma unroll
      for (int rr = 0; rr < 8; ++rr)
        kreg[rr] = *(const float4*)(kb + (size_t)(r0 + rr*8)*(NKVH*HD));
    }

    const bool active = (n0 <= q0 + w*32 + 31);
    if (active) {
      // ---- S = Q K^T (2 m-tiles x 64 keys), K frags shared across mi ----
      floatx4 sacc[MT][4];
      #pragma unroll
      for (int mi = 0; mi < MT; ++mi)
        #pragma unroll
        for (int sub = 0; sub < 4; ++sub) sacc[mi][sub] = (floatx4){0.f,0.f,0.f,0.f};
      #pragma unroll
      for (int sub = 0; sub < 4; ++sub) {
        #pragma unroll
        for (int dc = 0; dc < 4; ++dc) {
          short8v kf = *(const short8v*)(&ksh[(sub*16 + l15)*KSTR + dc*32 + quad*8]);
          #pragma unroll
          for (int mi = 0; mi < MT; ++mi)
            sacc[mi][sub] = __builtin_amdgcn_mfma_f32_16x16x32_bf16(qf[mi][dc], kf, sacc[mi][sub], 0, 0, 0);
        }
      }
      // ---- online softmax + P -> LDS (bf16) ----
      #pragma unroll
      for (int mi = 0; mi < MT; ++mi) {
        const int qbase = q0 + w*32 + mi*16;
        float s[4][4];
        const bool needMask = (n0 + BN - 1) > qbase;
        #pragma unroll
        for (int sub = 0; sub < 4; ++sub) {
          const int key = n0 + sub*16 + l15;
          #pragma unroll
          for (int r = 0; r < 4; ++r) {
            float sv = sacc[mi][sub][r];
            if (needMask && key > (qbase + quad*4 + r)) sv = -1e30f;
            s[sub][r] = sv;
          }
        }
        float mloc[4];
        #pragma unroll
        for (int r = 0; r < 4; ++r)
          mloc[r] = fmaxf(fmaxf(s[0][r], s[1][r]), fmaxf(s[2][r], s[3][r]));
        #pragma unroll
        for (int off = 1; off <= 8; off <<= 1)
          #pragma unroll
          for (int r = 0; r < 4; ++r)
            mloc[r] = fmaxf(mloc[r], __shfl_xor(mloc[r], off));
        float alpha[4], rs[4];
        #pragma unroll
        for (int r = 0; r < 4; ++r) {
          float mnew = fmaxf(mrun[mi][r], mloc[r]);
          alpha[r] = __expf(mrun[mi][r] - mnew);
          mrun[mi][r] = mnew;
          rs[r] = 0.f;
        }
        short* pw = &psh[((w*MT + mi)*16)*PSTR];
        #pragma unroll
        for (int sub = 0; sub < 4; ++sub) {
          #pragma unroll
          for (int r = 0; r < 4; ++r) {
            float p = __expf(s[sub][r] - mrun[mi][r]);
            rs[r] += p;
            pw[(quad*4 + r)*PSTR + sub*16 + l15] = f2bf(p);
          }
        }
        #pragma unroll
        for (int off = 1; off <= 8; off <<= 1)
          #pragma unroll
          for (int r = 0; r < 4; ++r)
            rs[r] += __shfl_xor(rs[r], off);
        #pragma unroll
        for (int r = 0; r < 4; ++r)
          lrun[mi][r] = lrun[mi][r]*alpha[r] + rs[r];
        #pragma unroll
        for (int dt = 0; dt < 8; ++dt)
          #pragma unroll
          for (int r = 0; r < 4; ++r)
            oacc[mi][dt][r] *= alpha[r];
      }
      // ---- P fragments (same-wave LDS RAW; DS ops in-order per wave) ----
      short8v pf[MT][2];
      #pragma unroll
      for (int mi = 0; mi < MT; ++mi)
        #pragma unroll
        for (int kc = 0; kc < 2; ++kc)
          pf[mi][kc] = *(const short8v*)(&psh[((w*MT + mi)*16 + l15)*PSTR + kc*32 + quad*8]);
      // ---- O += P V, V frags shared across mi ----
      #pragma unroll
      for (int dt = 0; dt < 8; ++dt) {
        #pragma unroll
        for (int kc = 0; kc < 2; ++kc) {
          const short* vb = &vsh[(dt*16 + l15)*VSTR + kc*32 + quad*8];
          short4v lo = *(const short4v*)(vb);
          short4v hi = *(const short4v*)(vb + 4);
          short8v vf;
          vf[0]=lo[0]; vf[1]=lo[1]; vf[2]=lo[2]; vf[3]=lo[3];
          vf[4]=hi[0]; vf[5]=hi[1]; vf[6]=hi[2]; vf[7]=hi[3];
          #pragma unroll
          for (int mi = 0; mi < MT; ++mi)
            oacc[mi][dt] = __builtin_amdgcn_mfma_f32_16x16x32_bf16(pf[mi][kc], vf, oacc[mi][dt], 0, 0, 0);
        }
      }
    }
  }

  // ---- epilogue: normalize and store ----
  #pragma unroll
  for (int mi = 0; mi < MT; ++mi) {
    float inv[4];
    #pragma unroll
    for (int r = 0; r < 4; ++r) inv[r] = 1.0f / lrun[mi][r];
    #pragma unroll
    for (int dt = 0; dt < 8; ++dt) {
      #pragma unroll
      for (int r = 0; r < 4; ++r) {
        const int qrow = q0 + w*32 + mi*16 + quad*4 + r;
        og[(size_t)(bb*SEQ + qrow)*(NHEADS*HD) + h*HD + dt*16 + l15] = oacc[mi][dt][r] * inv[r];
      }
    }
  }
}

// ---- KV cache: copy pristine input caches to output, then scatter rows ----
__global__ void cache_copy(const float4* __restrict__ kc_in, const float4* __restrict__ vc_in,
                           float4* __restrict__ kc_out, float4* __restrict__ vc_out, int n4)
{
  int i = blockIdx.x * blockDim.x + threadIdx.x;
  const int stride = gridDim.x * blockDim.x;
  for (; i < n4; i += stride) {
    kc_out[i] = kc_in[i];
    vc_out[i] = vc_in[i];
  }
}

__global__ void cache_scatter(const float4* __restrict__ k, const float4* __restrict__ v,
                              const int* __restrict__ slots,
                              float4* __restrict__ kc_out, float4* __restrict__ vc_out)
{
  const int i = blockIdx.x * blockDim.x + threadIdx.x;   // over STOK*256
  const int ROW4 = NKVH*HD/4;                            // 256 float4 per token row
  const int s = i >> 8, c = i & 255;
  const int slot = slots[s];
  kc_out[(size_t)slot*ROW4 + c] = k[i];
  vc_out[(size_t)slot*ROW4 + c] = v[i];
}

extern "C" void kernel_launch(void* const* d_in, const int* in_sizes, int n_in,
                              void* d_out, int out_size, void* d_ws, size_t ws_size,
                              hipStream_t stream)
{
  const float* q     = (const float*)d_in[0];
  const float* k     = (const float*)d_in[1];
  const float* v     = (const float*)d_in[2];
  const float* kc_in = (const float*)d_in[3];
  const float* vc_in = (const float*)d_in[4];
  const int*   slots = (const int*)d_in[5];

  float* o_out  = (float*)d_out;
  float* kc_out = o_out  + (size_t)STOK * NHEADS * HD;
  float* vc_out = kc_out + (size_t)NUM_SLOTS * NKVH * HD;

  attn_prefill<<<NHEADS*BATCH*QTILES, 256, 0, stream>>>(q, k, v, o_out);
  cache_copy<<<2048, 256, 0, stream>>>((const float4*)kc_in, (const float4*)vc_in,
                                       (float4*)kc_out, (float4*)vc_out,
                                       NUM_SLOTS*NKVH*HD/4);
  cache_scatter<<<(STOK*(NKVH*HD/4))/256, 256, 0, stream>>>((const float4*)k, (const float4*)v, slots,
                                                            (float4*)kc_out, (float4*)vc_out);
}

// Round 3
// 319.263 us; speedup vs baseline: 2.0374x; 1.4574x over previous
//
#include <hip/hip_runtime.h>

#define NHEADS 32
#define NKVH 8
#define HD 128
#define BATCH 4
#define SEQ 1024
#define STOK (BATCH*SEQ)
#define NUM_SLOTS 8192
#define SCALE 0.08838834764831845f
#define QTILES 8
#define BM 128
#define BN 64
#define MT 2
#define NATT (NHEADS*BATCH*QTILES)   // 1024 attention blocks
#define NCACHE 512                   // cache-writer blocks
#define SMEM_BYTES 73728             // 2*16K (K) + 2*16K (V) + 8K (P)

typedef __attribute__((ext_vector_type(8))) short short8v;
typedef __attribute__((ext_vector_type(4))) short short4v;
typedef __attribute__((ext_vector_type(4))) float floatx4;

__device__ __forceinline__ short f2bf(float f) {
  unsigned u = __builtin_bit_cast(unsigned, f);
  u += 0x7fffu + ((u >> 16) & 1u);
  return (short)(u >> 16);
}

#define GLD16(gp, lp) __builtin_amdgcn_global_load_lds( \
    (const __attribute__((address_space(1))) unsigned int*)(gp), \
    (__attribute__((address_space(3))) unsigned int*)(lp), 16, 0, 0)

// ---------------- prep: clear inverse slot map ----------------
__global__ void prep_clear(int* __restrict__ inv) {
  const int i = blockIdx.x * 256 + threadIdx.x;
  if (i < NUM_SLOTS) inv[i] = -1;
}

// ---------------- prep: build bf16 swizzled K/V images + inv map ----------------
// K image per (bb,kh): [key 0..1023][128 shorts], element (key,d) at
//   key*128 + ((d>>3) ^ (key&15))*8 + (d&7)
// V image per (bb,kh,tile): [d 0..127][64 shorts], element (d,klocal) at
//   d*64 + ((klocal>>3) ^ (d&7))*8 + (klocal&7)
__global__ __launch_bounds__(256)
void prep_build(const float* __restrict__ kg, const float* __restrict__ vg,
                const int* __restrict__ slots, int* __restrict__ inv,
                short* __restrict__ kimg, short* __restrict__ vimg)
{
  __shared__ __align__(16) short tile[8192];
  const int bx = blockIdx.x, tid = threadIdx.x;
  if (bx >= 512) {                       // inverse-map fill
    const int t = (bx - 512) * 256 + tid;
    if (t < STOK) inv[slots[t]] = t;
    return;
  }
  const int bb = bx >> 7, kh = (bx >> 4) & 7, ti = bx & 15;
  const int c4 = tid & 31, r0 = tid >> 5;
  // ---- K tile: cast + swizzle ----
  const float* kbase = kg + ((size_t)(bb*SEQ + ti*64))*(NKVH*HD) + kh*HD + c4*4;
  #pragma unroll
  for (int rr = 0; rr < 8; ++rr) {
    const int key = r0 + rr*8;
    float4 x = *(const float4*)(kbase + (size_t)key*(NKVH*HD));
    short4v s; s[0]=f2bf(x.x); s[1]=f2bf(x.y); s[2]=f2bf(x.z); s[3]=f2bf(x.w);
    const int chunk = (c4 >> 1) ^ (key & 15);
    *(short4v*)(&tile[key*128 + chunk*8 + (c4 & 1)*4]) = s;
  }
  __syncthreads();
  {
    uint4* dst = (uint4*)(kimg + ((size_t)((bb*8 + kh)*1024 + ti*64))*128);
    const uint4* src = (const uint4*)tile;
    #pragma unroll
    for (int q = 0; q < 4; ++q) dst[tid + q*256] = src[tid + q*256];
  }
  __syncthreads();
  // ---- V tile: transpose + cast + swizzle ----
  const float* vbase = vg + ((size_t)(bb*SEQ + ti*64))*(NKVH*HD) + kh*HD + c4*4;
  #pragma unroll
  for (int rr = 0; rr < 8; ++rr) {
    const int key = r0 + rr*8;
    float4 x = *(const float4*)(vbase + (size_t)key*(NKVH*HD));
    float e[4] = {x.x, x.y, x.z, x.w};
    #pragma unroll
    for (int j = 0; j < 4; ++j) {
      const int d = c4*4 + j;
      tile[d*64 + (((key >> 3) ^ (d & 7))*8) + (key & 7)] = f2bf(e[j]);
    }
  }
  __syncthreads();
  {
    uint4* dst = (uint4*)(vimg + ((size_t)((bb*8 + kh)*16 + ti))*8192);
    const uint4* src = (const uint4*)tile;
    #pragma unroll
    for (int q = 0; q < 4; ++q) dst[tid + q*256] = src[tid + q*256];
  }
}

// ---------------- fused attention + cache writer ----------------
__global__ __launch_bounds__(256, 2)
void fused_main(const float* __restrict__ qg,
                const float* __restrict__ kg, const float* __restrict__ vg,
                const float* __restrict__ kc_in, const float* __restrict__ vc_in,
                const int* __restrict__ inv,
                const short* __restrict__ kimg, const short* __restrict__ vimg,
                float* __restrict__ og,
                float* __restrict__ kc_out, float* __restrict__ vc_out)
{
  extern __shared__ __align__(16) short smem[];
  const int bx = blockIdx.x;
  const int tid = threadIdx.x;

  if (bx >= NATT) {
    // ---- cache writer: one coalesced pass, copy-or-scatter per slot ----
    const int cb = bx - NATT;
    const float4* kg4 = (const float4*)kg;
    const float4* vg4 = (const float4*)vg;
    const float4* kci = (const float4*)kc_in;
    const float4* vci = (const float4*)vc_in;
    float4* kco = (float4*)kc_out;
    float4* vco = (float4*)vc_out;
    #pragma unroll
    for (int s = 0; s < 16; ++s) {
      const int slot = cb*16 + s;
      const int t = inv[slot];
      const size_t o = (size_t)slot*256 + tid;
      kco[o] = (t >= 0) ? kg4[(size_t)t*256 + tid] : kci[o];
      vco[o] = (t >= 0) ? vg4[(size_t)t*256 + tid] : vci[o];
    }
    return;
  }

  // ---- attention block ----
  const int qt = (QTILES - 1) - (bx >> 7);   // LPT: longest first
  const int pair = bx & 127;
  const int h  = pair >> 2;
  const int bb = pair & 3;
  const int kh = h >> 2;
  const int w    = tid >> 6;
  const int lane = tid & 63;
  const int l15  = lane & 15;
  const int quad = lane >> 4;
  const int q0 = qt * BM;

  short* ksh = smem;                 // [2][8192]
  short* vsh = smem + 16384;         // [2][8192]
  short* pw  = smem + 32768 + w*1024;// per-wave [16][64] swizzled

  // Q fragments (pre-scaled bf16, A-layout)
  short8v qf[MT][4];
  #pragma unroll
  for (int mi = 0; mi < MT; ++mi) {
    const int qrow = q0 + w*32 + mi*16 + l15;
    const float* qp = qg + (size_t)(bb*SEQ + qrow)*(NHEADS*HD) + h*HD + quad*8;
    #pragma unroll
    for (int dc = 0; dc < 4; ++dc) {
      float4 a = *(const float4*)(qp + dc*32);
      float4 c = *(const float4*)(qp + dc*32 + 4);
      short8v f;
      f[0]=f2bf(a.x*SCALE); f[1]=f2bf(a.y*SCALE); f[2]=f2bf(a.z*SCALE); f[3]=f2bf(a.w*SCALE);
      f[4]=f2bf(c.x*SCALE); f[5]=f2bf(c.y*SCALE); f[6]=f2bf(c.z*SCALE); f[7]=f2bf(c.w*SCALE);
      qf[mi][dc] = f;
    }
  }

  floatx4 oacc[MT][8];
  float mrun[MT][4], lrun[MT][4];
  #pragma unroll
  for (int mi = 0; mi < MT; ++mi) {
    #pragma unroll
    for (int dt = 0; dt < 8; ++dt) oacc[mi][dt] = (floatx4){0.f,0.f,0.f,0.f};
    #pragma unroll
    for (int r = 0; r < 4; ++r) { mrun[mi][r] = -1e30f; lrun[mi][r] = 0.f; }
  }

  const short* kt0 = kimg + ((size_t)(bb*8 + kh)*1024)*128;
  const short* vt0 = vimg + ((size_t)(bb*8 + kh)*16)*8192;

  auto stage = [&](int it, int buf) {
    const char* kgp = (const char*)(kt0 + (size_t)it*8192) + w*4096 + lane*16;
    const char* vgp = (const char*)(vt0 + (size_t)it*8192) + w*4096 + lane*16;
    char* lk = (char*)(ksh + buf*8192) + w*4096;
    char* lv = (char*)(vsh + buf*8192) + w*4096;
    #pragma unroll
    for (int q2 = 0; q2 < 4; ++q2) {
      GLD16(kgp + q2*1024, lk + q2*1024);
      GLD16(vgp + q2*1024, lv + q2*1024);
    }
  };

  const int nTiles = 2*qt + 2;
  stage(0, 0);

  for (int it = 0; it < nTiles; ++it) {
    const int buf = it & 1;
    __syncthreads();                       // drains stage(it); protects buf^1 reuse
    if (it + 1 < nTiles) stage(it + 1, buf ^ 1);

    const int n0 = it * BN;
    if (n0 > q0 + w*32 + 31) continue;     // fully-masked for this wave

    const short* kb = ksh + buf*8192;
    const short* vb = vsh + buf*8192;

    // ---- S = Q K^T ----
    floatx4 sacc[MT][4];
    #pragma unroll
    for (int mi = 0; mi < MT; ++mi)
      #pragma unroll
      for (int sub = 0; sub < 4; ++sub) sacc[mi][sub] = (floatx4){0.f,0.f,0.f,0.f};
    #pragma unroll
    for (int sub = 0; sub < 4; ++sub) {
      #pragma unroll
      for (int dc = 0; dc < 4; ++dc) {
        short8v kf = *(const short8v*)(kb + (sub*16 + l15)*128 + (((dc*4 + quad) ^ l15)*8));
        #pragma unroll
        for (int mi = 0; mi < MT; ++mi)
          sacc[mi][sub] = __builtin_amdgcn_mfma_f32_16x16x32_bf16(qf[mi][dc], kf, sacc[mi][sub], 0, 0, 0);
      }
    }

    // ---- online softmax; P via per-wave LDS (read back before next mi) ----
    short8v pf[MT][2];
    #pragma unroll
    for (int mi = 0; mi < MT; ++mi) {
      const int qbase = q0 + w*32 + mi*16;
      float s[4][4];
      const bool needMask = (n0 + BN - 1) > qbase;
      #pragma unroll
      for (int sub = 0; sub < 4; ++sub) {
        const int key = n0 + sub*16 + l15;
        #pragma unroll
        for (int r = 0; r < 4; ++r) {
          float sv = sacc[mi][sub][r];
          if (needMask && key > (qbase + quad*4 + r)) sv = -1e30f;
          s[sub][r] = sv;
        }
      }
      float mloc[4];
      #pragma unroll
      for (int r = 0; r < 4; ++r)
        mloc[r] = fmaxf(fmaxf(s[0][r], s[1][r]), fmaxf(s[2][r], s[3][r]));
      #pragma unroll
      for (int off = 1; off <= 8; off <<= 1)
        #pragma unroll
        for (int r = 0; r < 4; ++r)
          mloc[r] = fmaxf(mloc[r], __shfl_xor(mloc[r], off));
      float alpha[4], rs[4];
      #pragma unroll
      for (int r = 0; r < 4; ++r) {
        float mnew = fmaxf(mrun[mi][r], mloc[r]);
        alpha[r] = __expf(mrun[mi][r] - mnew);
        mrun[mi][r] = mnew;
        rs[r] = 0.f;
      }
      #pragma unroll
      for (int sub = 0; sub < 4; ++sub) {
        #pragma unroll
        for (int r = 0; r < 4; ++r) {
          float p = __expf(s[sub][r] - mrun[mi][r]);
          rs[r] += p;
          const int row = quad*4 + r;
          pw[row*64 + (((sub*2 + (l15 >> 3)) ^ (row & 7))*8) + (l15 & 7)] = f2bf(p);
        }
      }
      #pragma unroll
      for (int off = 1; off <= 8; off <<= 1)
        #pragma unroll
        for (int r = 0; r < 4; ++r)
          rs[r] += __shfl_xor(rs[r], off);
      #pragma unroll
      for (int r = 0; r < 4; ++r)
        lrun[mi][r] = lrun[mi][r]*alpha[r] + rs[r];
      #pragma unroll
      for (int dt = 0; dt < 8; ++dt)
        #pragma unroll
        for (int r = 0; r < 4; ++r)
          oacc[mi][dt][r] *= alpha[r];
      // read A-layout P fragments (same-wave DS order guarantees RAW)
      #pragma unroll
      for (int kc = 0; kc < 2; ++kc)
        pf[mi][kc] = *(const short8v*)(pw + l15*64 + (((kc*4 + quad) ^ (l15 & 7))*8));
    }

    // ---- O += P V ----
    #pragma unroll
    for (int dt = 0; dt < 8; ++dt) {
      #pragma unroll
      for (int kc = 0; kc < 2; ++kc) {
        short8v vf = *(const short8v*)(vb + (dt*16 + l15)*64 + (((kc*4 + quad) ^ (l15 & 7))*8));
        #pragma unroll
        for (int mi = 0; mi < MT; ++mi)
          oacc[mi][dt] = __builtin_amdgcn_mfma_f32_16x16x32_bf16(pf[mi][kc], vf, oacc[mi][dt], 0, 0, 0);
      }
    }
  }

  // ---- epilogue ----
  #pragma unroll
  for (int mi = 0; mi < MT; ++mi) {
    float inv_l[4];
    #pragma unroll
    for (int r = 0; r < 4; ++r) inv_l[r] = 1.0f / lrun[mi][r];
    #pragma unroll
    for (int dt = 0; dt < 8; ++dt) {
      #pragma unroll
      for (int r = 0; r < 4; ++r) {
        const int qrow = q0 + w*32 + mi*16 + quad*4 + r;
        og[(size_t)(bb*SEQ + qrow)*(NHEADS*HD) + h*HD + dt*16 + l15] = oacc[mi][dt][r] * inv_l[r];
      }
    }
  }
}

extern "C" void kernel_launch(void* const* d_in, const int* in_sizes, int n_in,
                              void* d_out, int out_size, void* d_ws, size_t ws_size,
                              hipStream_t stream)
{
  const float* q     = (const float*)d_in[0];
  const float* k     = (const float*)d_in[1];
  const float* v     = (const float*)d_in[2];
  const float* kc_in = (const float*)d_in[3];
  const float* vc_in = (const float*)d_in[4];
  const int*   slots = (const int*)d_in[5];

  float* o_out  = (float*)d_out;
  float* kc_out = o_out  + (size_t)STOK * NHEADS * HD;
  float* vc_out = kc_out + (size_t)NUM_SLOTS * NKVH * HD;

  int*   inv  = (int*)d_ws;                                   // 32 KB
  short* kimg = (short*)((char*)d_ws + 32768);                // 8.39 MB
  short* vimg = (short*)((char*)d_ws + 32768 + 8388608);      // 8.39 MB

  hipFuncSetAttribute((const void*)fused_main,
                      hipFuncAttributeMaxDynamicSharedMemorySize, SMEM_BYTES);

  prep_clear<<<NUM_SLOTS/256, 256, 0, stream>>>(inv);
  prep_build<<<512 + STOK/256, 256, 0, stream>>>(k, v, slots, inv, kimg, vimg);
  fused_main<<<NATT + NCACHE, 256, SMEM_BYTES, stream>>>(q, k, v, kc_in, vc_in,
                                                         inv, kimg, vimg,
                                                         o_out, kc_out, vc_out);
}